// Round 2
// baseline (186.886 us; speedup 1.0000x reference)
//
#include <hip/hip_runtime.h>
#include <hip/hip_bf16.h>
#include <cstdint>

typedef __attribute__((ext_vector_type(8))) short short8;
typedef __attribute__((ext_vector_type(16))) float f32x16;

#if __has_builtin(__builtin_amdgcn_exp2f)
#define EXP2F(x) __builtin_amdgcn_exp2f(x)
#else
#define EXP2F(x) exp2f(x)
#endif

#define MFMA32(A, B, C) __builtin_amdgcn_mfma_f32_32x32x16_bf16((A), (B), (C), 0, 0, 0)

// fp32 -> bf16, round-to-nearest-even
__device__ __forceinline__ unsigned short f2bf(float f) {
  unsigned int u = __builtin_bit_cast(unsigned int, f);
  u += 0x7FFFu + ((u >> 16) & 1u);
  return (unsigned short)(u >> 16);
}

// ---------------------------------------------------------------------------
// Prep: Wt[which][n][k] = f2bf(W_which[k][n]),  3 x 64 x 512 bf16 (384 KB).
// Writes coalesced (k fastest); reads scattered but only 384 KB of source.
// ---------------------------------------------------------------------------
__global__ __launch_bounds__(256) void prep_wt(
    const float* __restrict__ Wq, const float* __restrict__ Wk,
    const float* __restrict__ Wv, unsigned short* __restrict__ Wt)
{
  int idx = blockIdx.x * 256 + threadIdx.x;     // 384 blocks -> 98304 threads
  int which = idx >> 15;
  int rem = idx & 32767;
  int n = rem >> 9;
  int k = rem & 511;
  const float* W = (which == 0) ? Wq : (which == 1) ? Wk : Wv;
  Wt[idx] = f2bf(W[k * 64 + n]);
}

// ---------------------------------------------------------------------------
// Q/K projection: Y = X[16384x512] * W[512x64] + b, bf16 out. NO LDS, no
// barriers: A-frags straight from global fp32 X (2x16B/lane/iter), B-frags
// straight from global bf16 Wt (L1/L2-resident, 2x16B/lane/iter). Wave = 32
// rows; grid (128, 2). Q (by=0) folds softmax scale (1/8)*log2(e).
// ---------------------------------------------------------------------------
__global__ __launch_bounds__(256) void proj_qk(
    const float* __restrict__ qin, const float* __restrict__ kin,
    const unsigned short* __restrict__ Wt,
    const float* __restrict__ bq, const float* __restrict__ bk,
    unsigned short* __restrict__ Qo, unsigned short* __restrict__ Ko)
{
  const int which = blockIdx.y;
  const float* X    = which ? kin : qin;
  const float* bias = which ? bk  : bq;
  unsigned short* Y = which ? Ko  : Qo;
  const unsigned short* wt = Wt + (size_t)which * 64 * 512;

  const int lane = threadIdx.x & 63;
  const int wave = threadIdx.x >> 6;
  const int h = lane >> 5, l31 = lane & 31;
  const int rowbase = blockIdx.x * 128 + wave * 32;
  const float* xrow = X + (size_t)(rowbase + l31) * 512 + h * 8;
  const unsigned short* w0 = wt + (size_t)l31 * 512 + h * 8;         // n = l31
  const unsigned short* w1 = w0 + 32 * 512;                          // n = l31+32

  f32x16 acc0 = {}, acc1 = {};
  #pragma unroll 4
  for (int kc = 0; kc < 32; ++kc) {
    float4 a0 = *(const float4*)(xrow + kc * 16);
    float4 a1 = *(const float4*)(xrow + kc * 16 + 4);
    short8 af = { (short)f2bf(a0.x), (short)f2bf(a0.y), (short)f2bf(a0.z), (short)f2bf(a0.w),
                  (short)f2bf(a1.x), (short)f2bf(a1.y), (short)f2bf(a1.z), (short)f2bf(a1.w) };
    short8 b0 = *(const short8*)(w0 + kc * 16);
    short8 b1 = *(const short8*)(w1 + kc * 16);
    acc0 = MFMA32(af, b0, acc0);
    acc1 = MFMA32(af, b1, acc1);
  }

  const float scale = which ? 1.0f : 0.18033688f;   // (1/sqrt(64))*log2(e) for Q
  const float bias0 = bias[l31], bias1 = bias[l31 + 32];
  #pragma unroll
  for (int r = 0; r < 16; ++r) {
    int row = (r & 3) + 8 * (r >> 2) + 4 * h;       // C/D layout [m101]
    size_t base = (size_t)(rowbase + row) * 64;
    Y[base + l31]      = f2bf((acc0[r] + bias0) * scale);
    Y[base + l31 + 32] = f2bf((acc1[r] + bias1) * scale);
  }
}

// ---------------------------------------------------------------------------
// V projection, output transposed: Vt[b][64][2048]. Same barrier-free main
// loop; LDS used only for the output transpose. TB stride 140 elems = 280 B:
// 8B-aligned rows (ushort4 reads), bank stride 70%32=6 -> <=4-way on the
// 2B scatter writes (epilogue-only, acceptable).
// ---------------------------------------------------------------------------
__global__ __launch_bounds__(256) void proj_v(
    const float* __restrict__ vin, const unsigned short* __restrict__ Wt,
    const float* __restrict__ bv, unsigned short* __restrict__ Vto)
{
  __shared__ unsigned short TB[64 * 140];   // 17.9 KB

  const int lane = threadIdx.x & 63;
  const int wave = threadIdx.x >> 6;
  const int h = lane >> 5, l31 = lane & 31;
  const int rowbase = blockIdx.x * 128 + wave * 32;
  const float* xrow = vin + (size_t)(rowbase + l31) * 512 + h * 8;
  const unsigned short* wt = Wt + (size_t)2 * 64 * 512;
  const unsigned short* w0 = wt + (size_t)l31 * 512 + h * 8;
  const unsigned short* w1 = w0 + 32 * 512;

  f32x16 acc0 = {}, acc1 = {};
  #pragma unroll 4
  for (int kc = 0; kc < 32; ++kc) {
    float4 a0 = *(const float4*)(xrow + kc * 16);
    float4 a1 = *(const float4*)(xrow + kc * 16 + 4);
    short8 af = { (short)f2bf(a0.x), (short)f2bf(a0.y), (short)f2bf(a0.z), (short)f2bf(a0.w),
                  (short)f2bf(a1.x), (short)f2bf(a1.y), (short)f2bf(a1.z), (short)f2bf(a1.w) };
    short8 b0 = *(const short8*)(w0 + kc * 16);
    short8 b1 = *(const short8*)(w1 + kc * 16);
    acc0 = MFMA32(af, b0, acc0);
    acc1 = MFMA32(af, b1, acc1);
  }

  const float bias0 = bv[l31], bias1 = bv[l31 + 32];
  #pragma unroll
  for (int r = 0; r < 16; ++r) {
    int row = (r & 3) + 8 * (r >> 2) + 4 * h;
    int sl = wave * 32 + row;
    TB[l31 * 140 + sl]        = f2bf(acc0[r] + bias0);
    TB[(l31 + 32) * 140 + sl] = f2bf(acc1[r] + bias1);
  }
  __syncthreads();
  int bidx = blockIdx.x >> 4;          // 16 blocks per batch (128 rows each)
  int s0 = (blockIdx.x & 15) * 128;
  for (int i = threadIdx.x; i < 64 * 32; i += 256) {   // 64 n x 32 ushort4 chunks
    int n = i >> 5, c = i & 31;
    ushort4 v4 = *(const ushort4*)(TB + n * 140 + c * 4);
    *(ushort4*)(Vto + ((size_t)bidx * 64 + n) * 2048 + s0 + c * 4) = v4;
  }
}

// ---------------------------------------------------------------------------
// Flash attention, transposed formulation (unchanged from round 1):
//   S^T = K * Q^T ; O^T = Vt * P^T. Key-reduction in-lane + shfl_xor(32);
//   P^T C->B relayout is a half-wave swap. WG = 8 waves, wave w owns keys
//   [256w, 256w+256); 8 partials tree-combined via LDS.
// ---------------------------------------------------------------------------
__global__ __launch_bounds__(512, 2) void attn_kernel(
    const unsigned short* __restrict__ Q, const unsigned short* __restrict__ K,
    const unsigned short* __restrict__ Vt, float* __restrict__ out)
{
  __shared__ float ObS[4][16][64];
  __shared__ float MpS[4][64];
  __shared__ float LpS[4][64];

  const int tid = threadIdx.x;
  const int lane = tid & 63, w = tid >> 6;
  const int h = lane >> 5, l31 = lane & 31;
  const int b = blockIdx.y;
  const int q0 = blockIdx.x * 64;

  short8 qf[2][4];
  #pragma unroll
  for (int qt = 0; qt < 2; ++qt) {
    const unsigned short* qp = Q + ((size_t)(b * 2048 + q0 + qt * 32 + l31)) * 64 + h * 8;
    #pragma unroll
    for (int c = 0; c < 4; ++c) qf[qt][c] = *(const short8*)(qp + c * 16);
  }

  f32x16 o00 = {}, o01 = {}, o10 = {}, o11 = {};
  float m0 = -1e30f, m1 = -1e30f, ls0 = 0.f, ls1 = 0.f;

  for (int st = 0; st < 8; ++st) {
    const int kb = w * 256 + st * 32;
    short8 kf[4];
    const unsigned short* kp = K + ((size_t)(b * 2048 + kb + l31)) * 64 + h * 8;
    #pragma unroll
    for (int c = 0; c < 4; ++c) kf[c] = *(const short8*)(kp + c * 16);
    short8 vf0[2], vf1[2];
    {
      const unsigned short* vp0 = Vt + ((size_t)(b * 64 + l31)) * 2048 + kb + h * 8;
      const unsigned short* vp1 = Vt + ((size_t)(b * 64 + 32 + l31)) * 2048 + kb + h * 8;
      vf0[0] = *(const short8*)(vp0);  vf0[1] = *(const short8*)(vp0 + 16);
      vf1[0] = *(const short8*)(vp1);  vf1[1] = *(const short8*)(vp1 + 16);
    }
    #pragma unroll
    for (int qt = 0; qt < 2; ++qt) {
      f32x16 sT = {};
      #pragma unroll
      for (int c = 0; c < 4; ++c) sT = MFMA32(kf[c], qf[qt][c], sT);
      float mx = sT[0];
      #pragma unroll
      for (int r = 1; r < 16; ++r) mx = fmaxf(mx, sT[r]);
      mx = fmaxf(mx, __shfl_xor(mx, 32, 64));
      float mold = qt ? m1 : m0;
      float mnew = fmaxf(mold, mx);
      float alpha = EXP2F(mold - mnew);
      float rs = 0.f;
      float p[16];
      #pragma unroll
      for (int r = 0; r < 16; ++r) { p[r] = EXP2F(sT[r] - mnew); rs += p[r]; }
      rs += __shfl_xor(rs, 32, 64);
      unsigned int pk[8];
      #pragma unroll
      for (int i = 0; i < 8; ++i)
        pk[i] = (unsigned int)f2bf(p[2 * i]) | ((unsigned int)f2bf(p[2 * i + 1]) << 16);
      unsigned int ex[8];
      #pragma unroll
      for (int i = 0; i < 8; ++i) ex[i] = (unsigned int)__shfl_xor((int)pk[i], 32, 64);
      uint4 cc0, cc1;
      if (h == 0) { cc0 = make_uint4(pk[0], pk[1], ex[0], ex[1]); cc1 = make_uint4(pk[4], pk[5], ex[4], ex[5]); }
      else        { cc0 = make_uint4(ex[2], ex[3], pk[2], pk[3]); cc1 = make_uint4(ex[6], ex[7], pk[6], pk[7]); }
      short8 P0 = __builtin_bit_cast(short8, cc0);
      short8 P1 = __builtin_bit_cast(short8, cc1);
      if (qt == 0) {
        m0 = mnew; ls0 = ls0 * alpha + rs;
        o00 *= alpha; o10 *= alpha;
        o00 = MFMA32(vf0[0], P0, o00); o00 = MFMA32(vf0[1], P1, o00);
        o10 = MFMA32(vf1[0], P0, o10); o10 = MFMA32(vf1[1], P1, o10);
      } else {
        m1 = mnew; ls1 = ls1 * alpha + rs;
        o01 *= alpha; o11 *= alpha;
        o01 = MFMA32(vf0[0], P0, o01); o01 = MFMA32(vf0[1], P1, o01);
        o11 = MFMA32(vf1[0], P0, o11); o11 = MFMA32(vf1[1], P1, o11);
      }
    }
  }

  for (int half = 4; half > 0; half >>= 1) {
    const bool writer = (w >= half) && (w < 2 * half);
    const bool merger = (w < half);
    __syncthreads();
    if (writer && h == 0) {
      MpS[w - half][l31] = m0;      LpS[w - half][l31] = ls0;
      MpS[w - half][32 + l31] = m1; LpS[w - half][32 + l31] = ls1;
    }
    __syncthreads();
    float fb0 = 0.f, fb1 = 0.f;
    if (merger) {
      float pm0 = MpS[w][l31],      pl0 = LpS[w][l31];
      float pm1 = MpS[w][32 + l31], pl1 = LpS[w][32 + l31];
      float nm0 = fmaxf(m0, pm0), nm1 = fmaxf(m1, pm1);
      float fa0 = EXP2F(m0 - nm0); fb0 = EXP2F(pm0 - nm0);
      float fa1 = EXP2F(m1 - nm1); fb1 = EXP2F(pm1 - nm1);
      m0 = nm0; m1 = nm1;
      ls0 = ls0 * fa0 + pl0 * fb0; ls1 = ls1 * fa1 + pl1 * fb1;
      o00 *= fa0; o10 *= fa0; o01 *= fa1; o11 *= fa1;
    }
    __syncthreads();
    if (writer) {
      #pragma unroll
      for (int r = 0; r < 16; ++r) ObS[w - half][r][lane] = o00[r]; }
    __syncthreads();
    if (merger) {
      #pragma unroll
      for (int r = 0; r < 16; ++r) o00[r] += ObS[w][r][lane] * fb0; }
    __syncthreads();
    if (writer) {
      #pragma unroll
      for (int r = 0; r < 16; ++r) ObS[w - half][r][lane] = o01[r]; }
    __syncthreads();
    if (merger) {
      #pragma unroll
      for (int r = 0; r < 16; ++r) o01[r] += ObS[w][r][lane] * fb1; }
    __syncthreads();
    if (writer) {
      #pragma unroll
      for (int r = 0; r < 16; ++r) ObS[w - half][r][lane] = o10[r]; }
    __syncthreads();
    if (merger) {
      #pragma unroll
      for (int r = 0; r < 16; ++r) o10[r] += ObS[w][r][lane] * fb0; }
    __syncthreads();
    if (writer) {
      #pragma unroll
      for (int r = 0; r < 16; ++r) ObS[w - half][r][lane] = o11[r]; }
    __syncthreads();
    if (merger) {
      #pragma unroll
      for (int r = 0; r < 16; ++r) o11[r] += ObS[w][r][lane] * fb1; }
  }

  if (w == 0) {
    float i0 = 1.0f / ls0, i1 = 1.0f / ls1;
    o00 *= i0; o10 *= i0; o01 *= i1; o11 *= i1;
    #pragma unroll
    for (int qt = 0; qt < 2; ++qt) {
      int q = qt * 32 + l31;
      float* ob = out + ((size_t)(b * 2048 + q0 + q)) * 64 + 4 * h;
      const f32x16 a = qt ? o01 : o00;
      const f32x16 c = qt ? o11 : o10;
      #pragma unroll
      for (int g = 0; g < 4; ++g) {
        *(float4*)(ob + 8 * g)      = make_float4(a[4*g], a[4*g+1], a[4*g+2], a[4*g+3]);
        *(float4*)(ob + 32 + 8 * g) = make_float4(c[4*g], c[4*g+1], c[4*g+2], c[4*g+3]);
      }
    }
  }
}

extern "C" void kernel_launch(void* const* d_in, const int* in_sizes, int n_in,
                              void* d_out, int out_size, void* d_ws, size_t ws_size,
                              hipStream_t stream) {
  const float* qin = (const float*)d_in[0];
  const float* kin = (const float*)d_in[1];
  const float* vin = (const float*)d_in[2];
  const float* Wq  = (const float*)d_in[3];
  const float* bq  = (const float*)d_in[4];
  const float* Wk  = (const float*)d_in[5];
  const float* bk  = (const float*)d_in[6];
  const float* Wv  = (const float*)d_in[7];
  const float* bv  = (const float*)d_in[8];

  unsigned short* Qo  = (unsigned short*)d_ws;            // [8*2048][64] bf16 (pre-scaled)
  unsigned short* Ko  = Qo + (size_t)16384 * 64;          // [8*2048][64] bf16
  unsigned short* Vto = Ko + (size_t)16384 * 64;          // [8][64][2048] bf16 (transposed)
  unsigned short* Wt  = Vto + (size_t)8 * 64 * 2048;      // [3][64][512] bf16 W^T
  float* out = (float*)d_out;

  hipLaunchKernelGGL(prep_wt, dim3(384), dim3(256), 0, stream, Wq, Wk, Wv, Wt);
  hipLaunchKernelGGL(proj_qk, dim3(128, 2), dim3(256), 0, stream,
                     qin, kin, Wt, bq, bk, Qo, Ko);
  hipLaunchKernelGGL(proj_v, dim3(128), dim3(256), 0, stream, vin, Wt, bv, Vto);
  hipLaunchKernelGGL(attn_kernel, dim3(32, 8), dim3(512), 0, stream, Qo, Ko, Vto, out);
}

// Round 3
// 171.469 us; speedup vs baseline: 1.0899x; 1.0899x over previous
//
#include <hip/hip_runtime.h>
#include <hip/hip_bf16.h>
#include <cstdint>

typedef __attribute__((ext_vector_type(8))) short short8;
typedef __attribute__((ext_vector_type(16))) float f32x16;

#if __has_builtin(__builtin_amdgcn_exp2f)
#define EXP2F(x) __builtin_amdgcn_exp2f(x)
#else
#define EXP2F(x) exp2f(x)
#endif

#define MFMA32(A, B, C) __builtin_amdgcn_mfma_f32_32x32x16_bf16((A), (B), (C), 0, 0, 0)

// fp32 -> bf16, round-to-nearest-even
__device__ __forceinline__ unsigned short f2bf(float f) {
  unsigned int u = __builtin_bit_cast(unsigned int, f);
  u += 0x7FFFu + ((u >> 16) & 1u);
  return (unsigned short)(u >> 16);
}

// ---------------------------------------------------------------------------
// Prep: Wt[which][n][k] = f2bf(W_which[k][n]),  3 x 64 x 512 bf16 (192 KB bf16).
// ---------------------------------------------------------------------------
__global__ __launch_bounds__(256) void prep_wt(
    const float* __restrict__ Wq, const float* __restrict__ Wk,
    const float* __restrict__ Wv, unsigned short* __restrict__ Wt)
{
  int idx = blockIdx.x * 256 + threadIdx.x;     // 384 blocks
  int which = idx >> 15;
  int rem = idx & 32767;
  int n = rem >> 9;
  int k = rem & 511;
  const float* W = (which == 0) ? Wq : (which == 1) ? Wk : Wv;
  Wt[idx] = f2bf(W[k * 64 + n]);
}

// ---------------------------------------------------------------------------
// Fused projection, split-K=2 for occupancy:
//   grid (256, 3): by = which (0:Q scaled, 1:K, 2:V transposed to Vt[b][64][2048])
//   block = 256 thr = 4 waves. wave w: grp = w&1 (rows blk*64 + 32*grp),
//   kh = w>>1 (K half). Barrier-free main loop: A-frags straight from global
//   fp32 X, B-frags straight from global bf16 Wt (L2-resident). kh=1 partials
//   combined via fp32 LDS (row stride 64 words == 0 mod 32 -> 2-way = free).
//   768 blocks = 3 blocks/CU = 12 waves/CU.
// ---------------------------------------------------------------------------
__global__ __launch_bounds__(256, 3) void proj_kernel(
    const float* __restrict__ qin, const float* __restrict__ kin,
    const float* __restrict__ vin, const unsigned short* __restrict__ Wt,
    const float* __restrict__ bq, const float* __restrict__ bk,
    const float* __restrict__ bv,
    unsigned short* __restrict__ Qo, unsigned short* __restrict__ Ko,
    unsigned short* __restrict__ Vto)
{
  __shared__ char smem_raw[16384];
  float* red = (float*)smem_raw;                 // [2][32][64] fp32 reduce buf
  unsigned short* TB = (unsigned short*)smem_raw; // [64][68] V-transpose buf

  const int which = blockIdx.y;
  const float* X    = (which == 0) ? qin : (which == 1) ? kin : vin;
  const float* bias = (which == 0) ? bq  : (which == 1) ? bk  : bv;

  const int lane = threadIdx.x & 63;
  const int wv = threadIdx.x >> 6;
  const int h = lane >> 5, l31 = lane & 31;
  const int grp = wv & 1;          // row group within block
  const int kh = wv >> 1;          // K half
  const int rowbase = blockIdx.x * 64 + grp * 32;

  const float* xrow = X + (size_t)(rowbase + l31) * 512 + kh * 256 + h * 8;
  const unsigned short* wbase = Wt + (size_t)which * 64 * 512 + kh * 256 + h * 8;
  const unsigned short* w0 = wbase + (size_t)l31 * 512;         // n = l31
  const unsigned short* w1 = w0 + 32 * 512;                     // n = l31+32

  f32x16 acc0 = {}, acc1 = {};
  #pragma unroll 4
  for (int kc = 0; kc < 16; ++kc) {
    float4 a0 = *(const float4*)(xrow + kc * 16);
    float4 a1 = *(const float4*)(xrow + kc * 16 + 4);
    short8 af = { (short)f2bf(a0.x), (short)f2bf(a0.y), (short)f2bf(a0.z), (short)f2bf(a0.w),
                  (short)f2bf(a1.x), (short)f2bf(a1.y), (short)f2bf(a1.z), (short)f2bf(a1.w) };
    short8 b0 = *(const short8*)(w0 + kc * 16);
    short8 b1 = *(const short8*)(w1 + kc * 16);
    acc0 = MFMA32(af, b0, acc0);
    acc1 = MFMA32(af, b1, acc1);
  }

  // split-K combine: kh=1 waves write partials, kh=0 waves add.
  if (kh == 1) {
    #pragma unroll
    for (int r = 0; r < 16; ++r) {
      int row = (r & 3) + 8 * (r >> 2) + 4 * h;   // C/D layout [m101]
      red[grp * 2048 + row * 64 + l31]      = acc0[r];
      red[grp * 2048 + row * 64 + l31 + 32] = acc1[r];
    }
  }
  __syncthreads();
  if (kh == 0) {
    #pragma unroll
    for (int r = 0; r < 16; ++r) {
      int row = (r & 3) + 8 * (r >> 2) + 4 * h;
      acc0[r] += red[grp * 2048 + row * 64 + l31];
      acc1[r] += red[grp * 2048 + row * 64 + l31 + 32];
    }
  }

  const float bias0 = bias[l31], bias1 = bias[l31 + 32];

  if (which < 2) {
    if (kh == 0) {
      const float scale = which ? 1.0f : 0.18033688f;  // (1/sqrt(64))*log2(e) for Q
      unsigned short* Y = which ? Ko : Qo;
      #pragma unroll
      for (int r = 0; r < 16; ++r) {
        int row = (r & 3) + 8 * (r >> 2) + 4 * h;
        size_t base = (size_t)(rowbase + row) * 64;
        Y[base + l31]      = f2bf((acc0[r] + bias0) * scale);
        Y[base + l31 + 32] = f2bf((acc1[r] + bias1) * scale);
      }
    }
  } else {
    __syncthreads();               // reduce-buffer reads done before TB overwrite
    if (kh == 0) {
      #pragma unroll
      for (int r = 0; r < 16; ++r) {
        int row = (r & 3) + 8 * (r >> 2) + 4 * h;
        int sl = grp * 32 + row;   // s within this block's 64 rows
        TB[l31 * 68 + sl]        = f2bf(acc0[r] + bias0);
        TB[(l31 + 32) * 68 + sl] = f2bf(acc1[r] + bias1);
      }
    }
    __syncthreads();
    int bidx = blockIdx.x >> 5;        // 32 blocks per batch (64 rows each)
    int s0 = (blockIdx.x & 31) * 64;
    for (int i = threadIdx.x; i < 64 * 16; i += 256) {   // 64 n x 16 ushort4 chunks
      int n = i >> 4, c = i & 15;
      ushort4 v4 = *(const ushort4*)(TB + n * 68 + c * 4);
      *(ushort4*)(Vto + ((size_t)bidx * 64 + n) * 2048 + s0 + c * 4) = v4;
    }
  }
}

// ---------------------------------------------------------------------------
// Flash attention, transposed formulation (unchanged):
//   S^T = K * Q^T ; O^T = Vt * P^T. Key-reduction in-lane + shfl_xor(32);
//   P^T C->B relayout is a half-wave swap. WG = 8 waves, wave w owns keys
//   [256w, 256w+256); 8 partials tree-combined via LDS.
// ---------------------------------------------------------------------------
__global__ __launch_bounds__(512, 2) void attn_kernel(
    const unsigned short* __restrict__ Q, const unsigned short* __restrict__ K,
    const unsigned short* __restrict__ Vt, float* __restrict__ out)
{
  __shared__ float ObS[4][16][64];
  __shared__ float MpS[4][64];
  __shared__ float LpS[4][64];

  const int tid = threadIdx.x;
  const int lane = tid & 63, w = tid >> 6;
  const int h = lane >> 5, l31 = lane & 31;
  const int b = blockIdx.y;
  const int q0 = blockIdx.x * 64;

  short8 qf[2][4];
  #pragma unroll
  for (int qt = 0; qt < 2; ++qt) {
    const unsigned short* qp = Q + ((size_t)(b * 2048 + q0 + qt * 32 + l31)) * 64 + h * 8;
    #pragma unroll
    for (int c = 0; c < 4; ++c) qf[qt][c] = *(const short8*)(qp + c * 16);
  }

  f32x16 o00 = {}, o01 = {}, o10 = {}, o11 = {};
  float m0 = -1e30f, m1 = -1e30f, ls0 = 0.f, ls1 = 0.f;

  for (int st = 0; st < 8; ++st) {
    const int kb = w * 256 + st * 32;
    short8 kf[4];
    const unsigned short* kp = K + ((size_t)(b * 2048 + kb + l31)) * 64 + h * 8;
    #pragma unroll
    for (int c = 0; c < 4; ++c) kf[c] = *(const short8*)(kp + c * 16);
    short8 vf0[2], vf1[2];
    {
      const unsigned short* vp0 = Vt + ((size_t)(b * 64 + l31)) * 2048 + kb + h * 8;
      const unsigned short* vp1 = Vt + ((size_t)(b * 64 + 32 + l31)) * 2048 + kb + h * 8;
      vf0[0] = *(const short8*)(vp0);  vf0[1] = *(const short8*)(vp0 + 16);
      vf1[0] = *(const short8*)(vp1);  vf1[1] = *(const short8*)(vp1 + 16);
    }
    #pragma unroll
    for (int qt = 0; qt < 2; ++qt) {
      f32x16 sT = {};
      #pragma unroll
      for (int c = 0; c < 4; ++c) sT = MFMA32(kf[c], qf[qt][c], sT);
      float mx = sT[0];
      #pragma unroll
      for (int r = 1; r < 16; ++r) mx = fmaxf(mx, sT[r]);
      mx = fmaxf(mx, __shfl_xor(mx, 32, 64));
      float mold = qt ? m1 : m0;
      float mnew = fmaxf(mold, mx);
      float alpha = EXP2F(mold - mnew);
      float rs = 0.f;
      float p[16];
      #pragma unroll
      for (int r = 0; r < 16; ++r) { p[r] = EXP2F(sT[r] - mnew); rs += p[r]; }
      rs += __shfl_xor(rs, 32, 64);
      unsigned int pk[8];
      #pragma unroll
      for (int i = 0; i < 8; ++i)
        pk[i] = (unsigned int)f2bf(p[2 * i]) | ((unsigned int)f2bf(p[2 * i + 1]) << 16);
      unsigned int ex[8];
      #pragma unroll
      for (int i = 0; i < 8; ++i) ex[i] = (unsigned int)__shfl_xor((int)pk[i], 32, 64);
      uint4 cc0, cc1;
      if (h == 0) { cc0 = make_uint4(pk[0], pk[1], ex[0], ex[1]); cc1 = make_uint4(pk[4], pk[5], ex[4], ex[5]); }
      else        { cc0 = make_uint4(ex[2], ex[3], pk[2], pk[3]); cc1 = make_uint4(ex[6], ex[7], pk[6], pk[7]); }
      short8 P0 = __builtin_bit_cast(short8, cc0);
      short8 P1 = __builtin_bit_cast(short8, cc1);
      if (qt == 0) {
        m0 = mnew; ls0 = ls0 * alpha + rs;
        o00 *= alpha; o10 *= alpha;
        o00 = MFMA32(vf0[0], P0, o00); o00 = MFMA32(vf0[1], P1, o00);
        o10 = MFMA32(vf1[0], P0, o10); o10 = MFMA32(vf1[1], P1, o10);
      } else {
        m1 = mnew; ls1 = ls1 * alpha + rs;
        o01 *= alpha; o11 *= alpha;
        o01 = MFMA32(vf0[0], P0, o01); o01 = MFMA32(vf0[1], P1, o01);
        o11 = MFMA32(vf1[0], P0, o11); o11 = MFMA32(vf1[1], P1, o11);
      }
    }
  }

  for (int half = 4; half > 0; half >>= 1) {
    const bool writer = (w >= half) && (w < 2 * half);
    const bool merger = (w < half);
    __syncthreads();
    if (writer && h == 0) {
      MpS[w - half][l31] = m0;      LpS[w - half][l31] = ls0;
      MpS[w - half][32 + l31] = m1; LpS[w - half][32 + l31] = ls1;
    }
    __syncthreads();
    float fb0 = 0.f, fb1 = 0.f;
    if (merger) {
      float pm0 = MpS[w][l31],      pl0 = LpS[w][l31];
      float pm1 = MpS[w][32 + l31], pl1 = LpS[w][32 + l31];
      float nm0 = fmaxf(m0, pm0), nm1 = fmaxf(m1, pm1);
      float fa0 = EXP2F(m0 - nm0); fb0 = EXP2F(pm0 - nm0);
      float fa1 = EXP2F(m1 - nm1); fb1 = EXP2F(pm1 - nm1);
      m0 = nm0; m1 = nm1;
      ls0 = ls0 * fa0 + pl0 * fb0; ls1 = ls1 * fa1 + pl1 * fb1;
      o00 *= fa0; o10 *= fa0; o01 *= fa1; o11 *= fa1;
    }
    __syncthreads();
    if (writer) {
      #pragma unroll
      for (int r = 0; r < 16; ++r) ObS[w - half][r][lane] = o00[r]; }
    __syncthreads();
    if (merger) {
      #pragma unroll
      for (int r = 0; r < 16; ++r) o00[r] += ObS[w][r][lane] * fb0; }
    __syncthreads();
    if (writer) {
      #pragma unroll
      for (int r = 0; r < 16; ++r) ObS[w - half][r][lane] = o01[r]; }
    __syncthreads();
    if (merger) {
      #pragma unroll
      for (int r = 0; r < 16; ++r) o01[r] += ObS[w][r][lane] * fb1; }
    __syncthreads();
    if (writer) {
      #pragma unroll
      for (int r = 0; r < 16; ++r) ObS[w - half][r][lane] = o10[r]; }
    __syncthreads();
    if (merger) {
      #pragma unroll
      for (int r = 0; r < 16; ++r) o10[r] += ObS[w][r][lane] * fb0; }
    __syncthreads();
    if (writer) {
      #pragma unroll
      for (int r = 0; r < 16; ++r) ObS[w - half][r][lane] = o11[r]; }
    __syncthreads();
    if (merger) {
      #pragma unroll
      for (int r = 0; r < 16; ++r) o11[r] += ObS[w][r][lane] * fb1; }
  }

  if (w == 0) {
    float i0 = 1.0f / ls0, i1 = 1.0f / ls1;
    o00 *= i0; o10 *= i0; o01 *= i1; o11 *= i1;
    #pragma unroll
    for (int qt = 0; qt < 2; ++qt) {
      int q = qt * 32 + l31;
      float* ob = out + ((size_t)(b * 2048 + q0 + q)) * 64 + 4 * h;
      const f32x16 a = qt ? o01 : o00;
      const f32x16 c = qt ? o11 : o10;
      #pragma unroll
      for (int g = 0; g < 4; ++g) {
        *(float4*)(ob + 8 * g)      = make_float4(a[4*g], a[4*g+1], a[4*g+2], a[4*g+3]);
        *(float4*)(ob + 32 + 8 * g) = make_float4(c[4*g], c[4*g+1], c[4*g+2], c[4*g+3]);
      }
    }
  }
}

extern "C" void kernel_launch(void* const* d_in, const int* in_sizes, int n_in,
                              void* d_out, int out_size, void* d_ws, size_t ws_size,
                              hipStream_t stream) {
  const float* qin = (const float*)d_in[0];
  const float* kin = (const float*)d_in[1];
  const float* vin = (const float*)d_in[2];
  const float* Wq  = (const float*)d_in[3];
  const float* bq  = (const float*)d_in[4];
  const float* Wk  = (const float*)d_in[5];
  const float* bk  = (const float*)d_in[6];
  const float* Wv  = (const float*)d_in[7];
  const float* bv  = (const float*)d_in[8];

  unsigned short* Qo  = (unsigned short*)d_ws;            // [8*2048][64] bf16 (pre-scaled)
  unsigned short* Ko  = Qo + (size_t)16384 * 64;          // [8*2048][64] bf16
  unsigned short* Vto = Ko + (size_t)16384 * 64;          // [8][64][2048] bf16 (transposed)
  unsigned short* Wt  = Vto + (size_t)8 * 64 * 2048;      // [3][64][512] bf16 W^T
  float* out = (float*)d_out;

  hipLaunchKernelGGL(prep_wt, dim3(384), dim3(256), 0, stream, Wq, Wk, Wv, Wt);
  hipLaunchKernelGGL(proj_kernel, dim3(256, 3), dim3(256), 0, stream,
                     qin, kin, vin, Wt, bq, bk, bv, Qo, Ko, Vto);
  hipLaunchKernelGGL(attn_kernel, dim3(32, 8), dim3(512), 0, stream, Qo, Ko, Vto, out);
}

// Round 4
// 162.257 us; speedup vs baseline: 1.1518x; 1.0568x over previous
//
#include <hip/hip_runtime.h>
#include <hip/hip_bf16.h>
#include <cstdint>

typedef __attribute__((ext_vector_type(8))) short short8;
typedef __attribute__((ext_vector_type(16))) float f32x16;

#if __has_builtin(__builtin_amdgcn_exp2f)
#define EXP2F(x) __builtin_amdgcn_exp2f(x)
#else
#define EXP2F(x) exp2f(x)
#endif

#define MFMA32(A, B, C) __builtin_amdgcn_mfma_f32_32x32x16_bf16((A), (B), (C), 0, 0, 0)

// fp32 -> bf16, round-to-nearest-even
__device__ __forceinline__ unsigned short f2bf(float f) {
  unsigned int u = __builtin_bit_cast(unsigned int, f);
  u += 0x7FFFu + ((u >> 16) & 1u);
  return (unsigned short)(u >> 16);
}

// ---------------------------------------------------------------------------
// Prep: Wt[which][n][k] = f2bf(W_which[k][n]),  3 x 64 x 512 bf16.
// ---------------------------------------------------------------------------
__global__ __launch_bounds__(256) void prep_wt(
    const float* __restrict__ Wq, const float* __restrict__ Wk,
    const float* __restrict__ Wv, unsigned short* __restrict__ Wt)
{
  int idx = blockIdx.x * 256 + threadIdx.x;     // 384 blocks
  int which = idx >> 15;
  int rem = idx & 32767;
  int n = rem >> 9;
  int k = rem & 511;
  const float* W = (which == 0) ? Wq : (which == 1) ? Wk : Wv;
  Wt[idx] = f2bf(W[k * 64 + n]);
}

// ---------------------------------------------------------------------------
// Fused projection, canonical LDS-staged GEMM (fixes the uncoalesced A-loads
// of rounds 1-3: every global X access is now a contiguous 512B row-run per
// half-wave; the MFMA's strided row access happens in LDS instead).
//   grid (256, 3): by = which (0:Q scaled, 1:K, 2:V -> Vt[b][64][2048]).
//   block = 256 = 4 waves: grp = wv&1 (rows), nh = wv>>1 (cols).
//   Tile M=64, N=64, BK=128, 4 chunks. Xs[64][136] bf16 (272B row stride:
//   16B-aligned, ds_write_b64/ds_read_b128 phases perfectly bank-balanced).
//   768 blocks = 3/CU so inter-block overlap hides the 2 barriers/chunk.
// ---------------------------------------------------------------------------
__global__ __launch_bounds__(256, 3) void proj_kernel(
    const float* __restrict__ qin, const float* __restrict__ kin,
    const float* __restrict__ vin, const unsigned short* __restrict__ Wt,
    const float* __restrict__ bq, const float* __restrict__ bk,
    const float* __restrict__ bv,
    unsigned short* __restrict__ Qo, unsigned short* __restrict__ Ko,
    unsigned short* __restrict__ Vto)
{
  __shared__ unsigned short Xs[64 * 136];   // 17.4 KB; reused as TB[64][68] for V

  const int which = blockIdx.y;
  const float* X    = (which == 0) ? qin : (which == 1) ? kin : vin;
  const float* bias = (which == 0) ? bq  : (which == 1) ? bk  : bv;

  const int tid = threadIdx.x;
  const int lane = tid & 63, wv = tid >> 6;
  const int h = lane >> 5, l31 = lane & 31;
  const int grp = wv & 1, nh = wv >> 1;
  const int m0 = blockIdx.x * 64;

  // W B-frag base: n = nh*32 + l31 on lanes, k = h*8 + j (L2-resident)
  const unsigned short* wcol =
      Wt + (size_t)which * 64 * 512 + (size_t)(nh * 32 + l31) * 512 + h * 8;

  // staging coords: thread covers row (tid>>5)+8j, 16B k-offset (tid&31)
  const int srow = tid >> 5;        // 0..7
  const int skoff = tid & 31;       // 16B units within 512B chunk-row
  const float* xg = X + (size_t)(m0 + srow) * 512 + skoff * 4;

  f32x16 acc = {};
  for (int c = 0; c < 4; ++c) {
    __syncthreads();                          // previous chunk's LDS reads done
    #pragma unroll
    for (int j = 0; j < 8; ++j) {
      float4 a = *(const float4*)(xg + (size_t)(8 * j) * 512 + c * 128);
      unsigned int w0 = (unsigned int)f2bf(a.x) | ((unsigned int)f2bf(a.y) << 16);
      unsigned int w1 = (unsigned int)f2bf(a.z) | ((unsigned int)f2bf(a.w) << 16);
      uint2 pw; pw.x = w0; pw.y = w1;
      *(uint2*)(&Xs[(srow + 8 * j) * 136 + skoff * 4]) = pw;
    }
    __syncthreads();
    const unsigned short* arow = &Xs[(grp * 32 + l31) * 136 + h * 8];
    const unsigned short* wk = wcol + c * 128;
    #pragma unroll
    for (int ks = 0; ks < 8; ++ks) {
      short8 af = *(const short8*)(arow + ks * 16);
      short8 bf = *(const short8*)(wk + ks * 16);
      acc = MFMA32(af, bf, acc);
    }
  }

  const float bv0 = bias[nh * 32 + l31];

  if (which < 2) {
    const float scale = which ? 1.0f : 0.18033688f;  // (1/sqrt(64))*log2(e) for Q
    unsigned short* Y = which ? Ko : Qo;
    #pragma unroll
    for (int r = 0; r < 16; ++r) {
      int row = (r & 3) + 8 * (r >> 2) + 4 * h;      // C/D layout [m101]
      Y[(size_t)(m0 + grp * 32 + row) * 64 + nh * 32 + l31] =
          f2bf((acc[r] + bv0) * scale);
    }
  } else {
    __syncthreads();                // all waves done with Xs before TB overwrite
    unsigned short* TB = Xs;        // [64 n][68 s]
    #pragma unroll
    for (int r = 0; r < 16; ++r) {
      int row = (r & 3) + 8 * (r >> 2) + 4 * h;
      TB[(nh * 32 + l31) * 68 + grp * 32 + row] = f2bf(acc[r] + bv0);
    }
    __syncthreads();
    int bidx = blockIdx.x >> 5;        // 32 blocks per batch (64 rows each)
    int s0 = (blockIdx.x & 31) * 64;
    for (int i = tid; i < 64 * 16; i += 256) {   // 64 n x 16 ushort4 chunks
      int n = i >> 4, cs = i & 15;
      ushort4 v4 = *(const ushort4*)(TB + n * 68 + cs * 4);
      *(ushort4*)(Vto + ((size_t)bidx * 64 + n) * 2048 + s0 + cs * 4) = v4;
    }
  }
}

// ---------------------------------------------------------------------------
// Flash attention, transposed formulation (unchanged):
//   S^T = K * Q^T ; O^T = Vt * P^T. Key-reduction in-lane + shfl_xor(32);
//   P^T C->B relayout is a half-wave swap. WG = 8 waves, wave w owns keys
//   [256w, 256w+256); 8 partials tree-combined via LDS.
// ---------------------------------------------------------------------------
__global__ __launch_bounds__(512, 2) void attn_kernel(
    const unsigned short* __restrict__ Q, const unsigned short* __restrict__ K,
    const unsigned short* __restrict__ Vt, float* __restrict__ out)
{
  __shared__ float ObS[4][16][64];
  __shared__ float MpS[4][64];
  __shared__ float LpS[4][64];

  const int tid = threadIdx.x;
  const int lane = tid & 63, w = tid >> 6;
  const int h = lane >> 5, l31 = lane & 31;
  const int b = blockIdx.y;
  const int q0 = blockIdx.x * 64;

  short8 qf[2][4];
  #pragma unroll
  for (int qt = 0; qt < 2; ++qt) {
    const unsigned short* qp = Q + ((size_t)(b * 2048 + q0 + qt * 32 + l31)) * 64 + h * 8;
    #pragma unroll
    for (int c = 0; c < 4; ++c) qf[qt][c] = *(const short8*)(qp + c * 16);
  }

  f32x16 o00 = {}, o01 = {}, o10 = {}, o11 = {};
  float m0 = -1e30f, m1 = -1e30f, ls0 = 0.f, ls1 = 0.f;

  for (int st = 0; st < 8; ++st) {
    const int kb = w * 256 + st * 32;
    short8 kf[4];
    const unsigned short* kp = K + ((size_t)(b * 2048 + kb + l31)) * 64 + h * 8;
    #pragma unroll
    for (int c = 0; c < 4; ++c) kf[c] = *(const short8*)(kp + c * 16);
    short8 vf0[2], vf1[2];
    {
      const unsigned short* vp0 = Vt + ((size_t)(b * 64 + l31)) * 2048 + kb + h * 8;
      const unsigned short* vp1 = Vt + ((size_t)(b * 64 + 32 + l31)) * 2048 + kb + h * 8;
      vf0[0] = *(const short8*)(vp0);  vf0[1] = *(const short8*)(vp0 + 16);
      vf1[0] = *(const short8*)(vp1);  vf1[1] = *(const short8*)(vp1 + 16);
    }
    #pragma unroll
    for (int qt = 0; qt < 2; ++qt) {
      f32x16 sT = {};
      #pragma unroll
      for (int c = 0; c < 4; ++c) sT = MFMA32(kf[c], qf[qt][c], sT);
      float mx = sT[0];
      #pragma unroll
      for (int r = 1; r < 16; ++r) mx = fmaxf(mx, sT[r]);
      mx = fmaxf(mx, __shfl_xor(mx, 32, 64));
      float mold = qt ? m1 : m0;
      float mnew = fmaxf(mold, mx);
      float alpha = EXP2F(mold - mnew);
      float rs = 0.f;
      float p[16];
      #pragma unroll
      for (int r = 0; r < 16; ++r) { p[r] = EXP2F(sT[r] - mnew); rs += p[r]; }
      rs += __shfl_xor(rs, 32, 64);
      unsigned int pk[8];
      #pragma unroll
      for (int i = 0; i < 8; ++i)
        pk[i] = (unsigned int)f2bf(p[2 * i]) | ((unsigned int)f2bf(p[2 * i + 1]) << 16);
      unsigned int ex[8];
      #pragma unroll
      for (int i = 0; i < 8; ++i) ex[i] = (unsigned int)__shfl_xor((int)pk[i], 32, 64);
      uint4 cc0, cc1;
      if (h == 0) { cc0 = make_uint4(pk[0], pk[1], ex[0], ex[1]); cc1 = make_uint4(pk[4], pk[5], ex[4], ex[5]); }
      else        { cc0 = make_uint4(ex[2], ex[3], pk[2], pk[3]); cc1 = make_uint4(ex[6], ex[7], pk[6], pk[7]); }
      short8 P0 = __builtin_bit_cast(short8, cc0);
      short8 P1 = __builtin_bit_cast(short8, cc1);
      if (qt == 0) {
        m0 = mnew; ls0 = ls0 * alpha + rs;
        o00 *= alpha; o10 *= alpha;
        o00 = MFMA32(vf0[0], P0, o00); o00 = MFMA32(vf0[1], P1, o00);
        o10 = MFMA32(vf1[0], P0, o10); o10 = MFMA32(vf1[1], P1, o10);
      } else {
        m1 = mnew; ls1 = ls1 * alpha + rs;
        o01 *= alpha; o11 *= alpha;
        o01 = MFMA32(vf0[0], P0, o01); o01 = MFMA32(vf0[1], P1, o01);
        o11 = MFMA32(vf1[0], P0, o11); o11 = MFMA32(vf1[1], P1, o11);
      }
    }
  }

  for (int half = 4; half > 0; half >>= 1) {
    const bool writer = (w >= half) && (w < 2 * half);
    const bool merger = (w < half);
    __syncthreads();
    if (writer && h == 0) {
      MpS[w - half][l31] = m0;      LpS[w - half][l31] = ls0;
      MpS[w - half][32 + l31] = m1; LpS[w - half][32 + l31] = ls1;
    }
    __syncthreads();
    float fb0 = 0.f, fb1 = 0.f;
    if (merger) {
      float pm0 = MpS[w][l31],      pl0 = LpS[w][l31];
      float pm1 = MpS[w][32 + l31], pl1 = LpS[w][32 + l31];
      float nm0 = fmaxf(m0, pm0), nm1 = fmaxf(m1, pm1);
      float fa0 = EXP2F(m0 - nm0); fb0 = EXP2F(pm0 - nm0);
      float fa1 = EXP2F(m1 - nm1); fb1 = EXP2F(pm1 - nm1);
      m0 = nm0; m1 = nm1;
      ls0 = ls0 * fa0 + pl0 * fb0; ls1 = ls1 * fa1 + pl1 * fb1;
      o00 *= fa0; o10 *= fa0; o01 *= fa1; o11 *= fa1;
    }
    __syncthreads();
    if (writer) {
      #pragma unroll
      for (int r = 0; r < 16; ++r) ObS[w - half][r][lane] = o00[r]; }
    __syncthreads();
    if (merger) {
      #pragma unroll
      for (int r = 0; r < 16; ++r) o00[r] += ObS[w][r][lane] * fb0; }
    __syncthreads();
    if (writer) {
      #pragma unroll
      for (int r = 0; r < 16; ++r) ObS[w - half][r][lane] = o01[r]; }
    __syncthreads();
    if (merger) {
      #pragma unroll
      for (int r = 0; r < 16; ++r) o01[r] += ObS[w][r][lane] * fb1; }
    __syncthreads();
    if (writer) {
      #pragma unroll
      for (int r = 0; r < 16; ++r) ObS[w - half][r][lane] = o10[r]; }
    __syncthreads();
    if (merger) {
      #pragma unroll
      for (int r = 0; r < 16; ++r) o10[r] += ObS[w][r][lane] * fb0; }
    __syncthreads();
    if (writer) {
      #pragma unroll
      for (int r = 0; r < 16; ++r) ObS[w - half][r][lane] = o11[r]; }
    __syncthreads();
    if (merger) {
      #pragma unroll
      for (int r = 0; r < 16; ++r) o11[r] += ObS[w][r][lane] * fb1; }
  }

  if (w == 0) {
    float i0 = 1.0f / ls0, i1 = 1.0f / ls1;
    o00 *= i0; o10 *= i0; o01 *= i1; o11 *= i1;
    #pragma unroll
    for (int qt = 0; qt < 2; ++qt) {
      int q = qt * 32 + l31;
      float* ob = out + ((size_t)(b * 2048 + q0 + q)) * 64 + 4 * h;
      const f32x16 a = qt ? o01 : o00;
      const f32x16 c = qt ? o11 : o10;
      #pragma unroll
      for (int g = 0; g < 4; ++g) {
        *(float4*)(ob + 8 * g)      = make_float4(a[4*g], a[4*g+1], a[4*g+2], a[4*g+3]);
        *(float4*)(ob + 32 + 8 * g) = make_float4(c[4*g], c[4*g+1], c[4*g+2], c[4*g+3]);
      }
    }
  }
}

extern "C" void kernel_launch(void* const* d_in, const int* in_sizes, int n_in,
                              void* d_out, int out_size, void* d_ws, size_t ws_size,
                              hipStream_t stream) {
  const float* qin = (const float*)d_in[0];
  const float* kin = (const float*)d_in[1];
  const float* vin = (const float*)d_in[2];
  const float* Wq  = (const float*)d_in[3];
  const float* bq  = (const float*)d_in[4];
  const float* Wk  = (const float*)d_in[5];
  const float* bk  = (const float*)d_in[6];
  const float* Wv  = (const float*)d_in[7];
  const float* bv  = (const float*)d_in[8];

  unsigned short* Qo  = (unsigned short*)d_ws;            // [8*2048][64] bf16 (pre-scaled)
  unsigned short* Ko  = Qo + (size_t)16384 * 64;          // [8*2048][64] bf16
  unsigned short* Vto = Ko + (size_t)16384 * 64;          // [8][64][2048] bf16 (transposed)
  unsigned short* Wt  = Vto + (size_t)8 * 64 * 2048;      // [3][64][512] bf16 W^T
  float* out = (float*)d_out;

  hipLaunchKernelGGL(prep_wt, dim3(384), dim3(256), 0, stream, Wq, Wk, Wv, Wt);
  hipLaunchKernelGGL(proj_kernel, dim3(256, 3), dim3(256), 0, stream,
                     qin, kin, vin, Wt, bq, bk, bv, Qo, Ko, Vto);
  hipLaunchKernelGGL(attn_kernel, dim3(32, 8), dim3(512), 0, stream, Qo, Ko, Vto, out);
}